// Round 3
// baseline (1300.152 us; speedup 1.0000x reference)
//
#include <hip/hip_runtime.h>

#define NN 100000
#define NE 1600000
#define INF 128
#define HID 64
#define LN_EPS 1e-5f

#define BINB 9
#define BINSZ 512
#define NBIN 196   // ceil(100000/512)

// ---------------- CSR build via binned counting sort ----------------

__global__ __launch_bounds__(256) void k_zero(int* __restrict__ bincnt) {
    int i = threadIdx.x;
    if (i < NBIN) bincnt[i] = 0;
}

__global__ __launch_bounds__(256) void k_binhist(const int* __restrict__ dst, int* __restrict__ bincnt) {
    __shared__ int h[NBIN];
    for (int i = threadIdx.x; i < NBIN; i += 256) h[i] = 0;
    __syncthreads();
    int stride = gridDim.x * 256;
    for (int e = blockIdx.x * 256 + threadIdx.x; e < NE; e += stride)
        atomicAdd(&h[dst[e] >> BINB], 1);
    __syncthreads();
    for (int i = threadIdx.x; i < NBIN; i += 256)
        if (h[i]) atomicAdd(&bincnt[i], h[i]);
}

__global__ __launch_bounds__(256) void k_binscan(const int* __restrict__ bincnt, int* __restrict__ binptr,
                                                 int* __restrict__ bincur, int* __restrict__ rowptr) {
    int tid = threadIdx.x, lane = tid & 63, wid = tid >> 6;
    int x = (tid < NBIN) ? bincnt[tid] : 0;
    int v = x;
    #pragma unroll
    for (int d = 1; d < 64; d <<= 1) { int y = __shfl_up(v, d); if (lane >= d) v += y; }
    __shared__ int wsum[4];
    if (lane == 63) wsum[wid] = v;
    __syncthreads();
    int add = 0;
    for (int w = 0; w < wid; ++w) add += wsum[w];
    int excl = v + add - x;
    if (tid < NBIN) { binptr[tid] = excl; bincur[tid] = excl; }
    if (tid == 0) { binptr[NBIN] = NE; rowptr[NN] = NE; }
}

__global__ __launch_bounds__(256) void k_binfill(const int* __restrict__ src, const int* __restrict__ dst,
                                                 int* __restrict__ bincur, unsigned* __restrict__ binpair) {
    int e = blockIdx.x * 256 + threadIdx.x;
    if (e < NE) {
        int d = dst[e];
        int b = d >> BINB;
        int pos = atomicAdd(&bincur[b], 1);
        binpair[pos] = ((unsigned)src[e] << BINB) | (unsigned)(d & (BINSZ - 1));
    }
}

__global__ __launch_bounds__(256) void k_binsort(const unsigned* __restrict__ binpair,
                                                 const int* __restrict__ binptr,
                                                 int* __restrict__ rowptr, int* __restrict__ eidx) {
    __shared__ int cnt[BINSZ];
    __shared__ int ofs[BINSZ];
    __shared__ int cur[BINSZ];
    int tid = threadIdx.x, lane = tid & 63, wid = tid >> 6;
    int b = blockIdx.x;
    int s = binptr[b], t = binptr[b + 1];

    cnt[tid] = 0; cnt[tid + 256] = 0;
    __syncthreads();
    for (int e = s + tid; e < t; e += 256) atomicAdd(&cnt[binpair[e] & (BINSZ - 1)], 1);
    __syncthreads();

    // exclusive scan of cnt[512] with 256 threads (2 elems/thread)
    int a0 = cnt[2 * tid], a1 = cnt[2 * tid + 1];
    int ps = a0 + a1;
    int v = ps;
    #pragma unroll
    for (int d = 1; d < 64; d <<= 1) { int y = __shfl_up(v, d); if (lane >= d) v += y; }
    __shared__ int wsum[4];
    if (lane == 63) wsum[wid] = v;
    __syncthreads();
    int add = 0;
    for (int w = 0; w < wid; ++w) add += wsum[w];
    int excl = v + add - ps;
    ofs[2 * tid] = excl; ofs[2 * tid + 1] = excl + a0;
    cur[2 * tid] = excl; cur[2 * tid + 1] = excl + a0;
    __syncthreads();

    // rowptr for this bin's nodes
    int nodeBase = b << BINB;
    #pragma unroll
    for (int j = 0; j < 2; ++j) {
        int i = tid + j * 256;
        int n = nodeBase + i;
        if (n < NN) rowptr[n] = s + ofs[i];
    }

    // place srcs
    for (int e = s + tid; e < t; e += 256) {
        unsigned p = binpair[e];
        int l = p & (BINSZ - 1);
        int pos = s + atomicAdd(&cur[l], 1);
        eidx[pos] = (int)(p >> BINB);
    }
}

// ---------------- fused Linear + LayerNorm + ReLU ----------------
// wave = 4 nodes, lane = output feature. W staged in LDS; 16 node-rows/block staged in LDS.
// NOTE: hout may alias in0 (in-place, node-wise) -> no __restrict__ on these.

__device__ __forceinline__ float wave_sum64(float v) {
    #pragma unroll
    for (int d = 32; d >= 1; d >>= 1) v += __shfl_xor(v, d);
    return v;
}

__global__ __launch_bounds__(256) void k_mlp(
    const float* in0, int s0,
    const float* in1, int s1,
    const float* __restrict__ W,   const float* __restrict__ bias,
    const float* __restrict__ gam, const float* __restrict__ bet,
    float* hout, int ostride)
{
    __shared__ float sW[INF * HID];      // 32 KB
    __shared__ float sV[16 * INF];       // 8 KB: 16 node-rows of 128
    __shared__ float sB[HID], sG[HID], sBe[HID];

    int tid = threadIdx.x, lane = tid & 63, wid = tid >> 6;

    {   // stage W (+params) once
        const float4* Wg = (const float4*)W;
        float4* sW4 = (float4*)sW;
        #pragma unroll
        for (int j = 0; j < 8; ++j) sW4[tid + j * 256] = Wg[tid + j * 256];
        if (tid < HID) { sB[tid] = bias[tid]; sG[tid] = gam[tid]; sBe[tid] = bet[tid]; }
    }

    const int NG = NN / 16;  // 6250 groups of 16 nodes
    for (int g = blockIdx.x; g < NG; g += gridDim.x) {
        int base = g * 16;
        __syncthreads();
        {   // stage 16 rows (512 float4): coalesced
            float4* sV4 = (float4*)sV;
            #pragma unroll
            for (int t = 0; t < 2; ++t) {
                int f4 = tid + t * 256;
                int nl = f4 >> 5, k4 = f4 & 31;
                int n = base + nl;
                const float* p = (k4 < 16) ? (in0 + (size_t)n * s0 + k4 * 4)
                                           : (in1 + (size_t)n * s1 + (k4 - 16) * 4);
                sV4[f4] = *(const float4*)p;
            }
        }
        __syncthreads();

        const float4* v0 = (const float4*)sV + (wid * 4 + 0) * 32;
        const float4* v1 = v0 + 32;
        const float4* v2 = v0 + 64;
        const float4* v3 = v0 + 96;
        float acc0 = 0.f, acc1 = 0.f, acc2 = 0.f, acc3 = 0.f;
        #pragma unroll
        for (int k4 = 0; k4 < 32; ++k4) {
            float4 a = v0[k4], b = v1[k4], c = v2[k4], d = v3[k4];
            const float* wrow = &sW[k4 * 4 * HID + lane];
            float w0 = wrow[0], w1 = wrow[64], w2 = wrow[128], w3 = wrow[192];
            acc0 = fmaf(a.x, w0, acc0); acc0 = fmaf(a.y, w1, acc0);
            acc0 = fmaf(a.z, w2, acc0); acc0 = fmaf(a.w, w3, acc0);
            acc1 = fmaf(b.x, w0, acc1); acc1 = fmaf(b.y, w1, acc1);
            acc1 = fmaf(b.z, w2, acc1); acc1 = fmaf(b.w, w3, acc1);
            acc2 = fmaf(c.x, w0, acc2); acc2 = fmaf(c.y, w1, acc2);
            acc2 = fmaf(c.z, w2, acc2); acc2 = fmaf(c.w, w3, acc2);
            acc3 = fmaf(d.x, w0, acc3); acc3 = fmaf(d.y, w1, acc3);
            acc3 = fmaf(d.z, w2, acc3); acc3 = fmaf(d.w, w3, acc3);
        }

        int n0 = base + wid * 4;
        float accs[4] = {acc0, acc1, acc2, acc3};
        #pragma unroll
        for (int p = 0; p < 4; ++p) {
            float acc = accs[p] + sB[lane];
            float s  = wave_sum64(acc);
            float ss = wave_sum64(acc * acc);
            float mu  = s * 0.015625f;
            float var = fmaxf(ss * 0.015625f - mu * mu, 0.f);
            float rs  = rsqrtf(var + LN_EPS);
            float o   = (acc - mu) * rs * sG[lane] + sBe[lane];
            hout[(size_t)(n0 + p) * ostride + lane] = fmaxf(o, 0.f);
        }
    }
}

// ---------------- per-dst segment max (gather over CSR) ----------------
// wave per node, lane = feature. h >= 0 (post-ReLU) so init 0 is the max identity.

__global__ __launch_bounds__(256) void k_gather(
    const float* __restrict__ h, int hstride,
    const int* __restrict__ rowptr, const int* __restrict__ eidx,
    float* __restrict__ agg, int astride)
{
    int lane = threadIdx.x & 63;
    int n = blockIdx.x * 4 + (threadIdx.x >> 6);
    if (n >= NN) return;
    int start = rowptr[n], end = rowptr[n + 1];
    float m;
    if (start == end) {
        m = h[(size_t)n * hstride + lane];   // no in-edges: keep own feature
    } else {
        m = 0.f;
        int e = start;
        for (; e + 4 <= end; e += 4) {
            int i0 = eidx[e], i1 = eidx[e + 1], i2 = eidx[e + 2], i3 = eidx[e + 3];
            float a = h[(size_t)i0 * hstride + lane], b = h[(size_t)i1 * hstride + lane];
            float c = h[(size_t)i2 * hstride + lane], d = h[(size_t)i3 * hstride + lane];
            m = fmaxf(m, fmaxf(fmaxf(a, b), fmaxf(c, d)));
        }
        for (; e < end; ++e) m = fmaxf(m, h[(size_t)eidx[e] * hstride + lane]);
    }
    agg[(size_t)n * astride + lane] = m;
}

// ---------------- launch ----------------

extern "C" void kernel_launch(void* const* d_in, const int* in_sizes, int n_in,
                              void* d_out, int out_size, void* d_ws, size_t ws_size,
                              hipStream_t stream) {
    const float* inputs = (const float*)d_in[0];
    const int*   src    = (const int*)d_in[1];
    const int*   dst    = (const int*)d_in[2];
    const float* Ws     = (const float*)d_in[3];
    const float* bs     = (const float*)d_in[4];
    const float* gs     = (const float*)d_in[5];
    const float* bes    = (const float*)d_in[6];
    float* out = (float*)d_out;

    char* w = (char*)d_ws;
    int* bincnt = (int*)w; w += 256 * 4;
    int* binptr = (int*)w; w += 256 * 4;
    int* bincur = (int*)w; w += 256 * 4;
    int* rowptr = (int*)w; w += (size_t)(NN + 1) * 4;
    int* eidx   = (int*)w; w += (size_t)NE * 4;
    uintptr_t a = (uintptr_t)w; a = (a + 255) & ~(uintptr_t)255; w = (char*)a;
    float* hA   = (float*)w; w += (size_t)NN * HID * 4;
    float* aggA = (float*)w; w += (size_t)NN * HID * 4;
    // binpair aliases aggA's space: dead before aggA's first write (stream-ordered)
    unsigned* binpair = (unsigned*)aggA;

    // CSR build (graph is layer-invariant within a call)
    k_zero   <<<1,    256, 0, stream>>>(bincnt);
    k_binhist<<<391,  256, 0, stream>>>(dst, bincnt);
    k_binscan<<<1,    256, 0, stream>>>(bincnt, binptr, bincur, rowptr);
    k_binfill<<<6250, 256, 0, stream>>>(src, dst, bincur, binpair);
    k_binsort<<<NBIN, 256, 0, stream>>>(binpair, binptr, rowptr, eidx);

    // layer 0: inputs -> hA, aggA
    k_mlp   <<<1250, 256, 0, stream>>>(inputs, INF, inputs + HID, INF, Ws, bs, gs, bes, hA, HID);
    k_gather<<<25000, 256, 0, stream>>>(hA, HID, rowptr, eidx, aggA, HID);
    // layer 1: in-place (node-wise map; block stages its 16 rows before storing)
    k_mlp   <<<1250, 256, 0, stream>>>(hA, HID, aggA, HID, Ws + 8192, bs + 64, gs + 64, bes + 64, hA, HID);
    k_gather<<<25000, 256, 0, stream>>>(hA, HID, rowptr, eidx, aggA, HID);
    // layer 2: h -> out interleaved [n][0:64], agg -> out [n][64:128]
    k_mlp   <<<1250, 256, 0, stream>>>(hA, HID, aggA, HID, Ws + 16384, bs + 128, gs + 128, bes + 128, out, 2 * HID);
    k_gather<<<25000, 256, 0, stream>>>(out, 2 * HID, rowptr, eidx, out + HID, 2 * HID);
}

// Round 4
// 424.334 us; speedup vs baseline: 3.0640x; 3.0640x over previous
//
#include <hip/hip_runtime.h>

#define NN 100000
#define NE 1600000
#define INF 128
#define HID 64
#define LN_EPS 1e-5f

#define BINB 9
#define BINSZ 512
#define NBIN 196   // ceil(100000/512)
#define FILLB 512  // blocks in k_binfill

// ---------------- CSR build via binned counting sort ----------------

__global__ __launch_bounds__(256) void k_zero(int* __restrict__ bincnt) {
    int i = threadIdx.x;
    if (i < NBIN) bincnt[i] = 0;
}

__global__ __launch_bounds__(256) void k_binhist(const int* __restrict__ dst, int* __restrict__ bincnt) {
    __shared__ int h[NBIN];
    for (int i = threadIdx.x; i < NBIN; i += 256) h[i] = 0;
    __syncthreads();
    int stride = gridDim.x * 256;
    for (int e = blockIdx.x * 256 + threadIdx.x; e < NE; e += stride)
        atomicAdd(&h[dst[e] >> BINB], 1);
    __syncthreads();
    for (int i = threadIdx.x; i < NBIN; i += 256)
        if (h[i]) atomicAdd(&bincnt[i], h[i]);
}

__global__ __launch_bounds__(256) void k_binscan(const int* __restrict__ bincnt, int* __restrict__ binptr,
                                                 int* __restrict__ bincur, int* __restrict__ rowptr) {
    int tid = threadIdx.x, lane = tid & 63, wid = tid >> 6;
    int x = (tid < NBIN) ? bincnt[tid] : 0;
    int v = x;
    #pragma unroll
    for (int d = 1; d < 64; d <<= 1) { int y = __shfl_up(v, d); if (lane >= d) v += y; }
    __shared__ int wsum[4];
    if (lane == 63) wsum[wid] = v;
    __syncthreads();
    int add = 0;
    for (int w = 0; w < wid; ++w) add += wsum[w];
    int excl = v + add - x;
    if (tid < NBIN) { binptr[tid] = excl; bincur[tid] = excl; }
    if (tid == 0) { binptr[NBIN] = NE; rowptr[NN] = NE; }
}

// block-privatized: LDS histogram -> one global atomicAdd per (block,bin) -> LDS-cursor placement
__global__ __launch_bounds__(256) void k_binfill(const int* __restrict__ src, const int* __restrict__ dst,
                                                 int* __restrict__ bincur, unsigned* __restrict__ binpair) {
    __shared__ int cnt[NBIN];
    __shared__ int base[NBIN];
    __shared__ int cur[NBIN];
    int tid = threadIdx.x;
    const int chunk = (NE + FILLB - 1) / FILLB;          // 3125
    int s = blockIdx.x * chunk;
    int t = min(s + chunk, NE);

    for (int i = tid; i < NBIN; i += 256) cnt[i] = 0;
    __syncthreads();
    for (int e = s + tid; e < t; e += 256) atomicAdd(&cnt[dst[e] >> BINB], 1);
    __syncthreads();
    for (int i = tid; i < NBIN; i += 256) {
        int c = cnt[i];
        base[i] = c ? atomicAdd(&bincur[i], c) : 0;
        cur[i] = 0;
    }
    __syncthreads();
    for (int e = s + tid; e < t; e += 256) {
        int d = dst[e];
        int b = d >> BINB;
        int pos = base[b] + atomicAdd(&cur[b], 1);
        binpair[pos] = ((unsigned)src[e] << BINB) | (unsigned)(d & (BINSZ - 1));
    }
}

__global__ __launch_bounds__(256) void k_binsort(const unsigned* __restrict__ binpair,
                                                 const int* __restrict__ binptr,
                                                 int* __restrict__ rowptr, int* __restrict__ eidx) {
    __shared__ int cnt[BINSZ];
    __shared__ int ofs[BINSZ];
    __shared__ int cur[BINSZ];
    int tid = threadIdx.x, lane = tid & 63, wid = tid >> 6;
    int b = blockIdx.x;
    int s = binptr[b], t = binptr[b + 1];

    cnt[tid] = 0; cnt[tid + 256] = 0;
    __syncthreads();
    for (int e = s + tid; e < t; e += 256) atomicAdd(&cnt[binpair[e] & (BINSZ - 1)], 1);
    __syncthreads();

    // exclusive scan of cnt[512] with 256 threads (2 elems/thread)
    int a0 = cnt[2 * tid], a1 = cnt[2 * tid + 1];
    int ps = a0 + a1;
    int v = ps;
    #pragma unroll
    for (int d = 1; d < 64; d <<= 1) { int y = __shfl_up(v, d); if (lane >= d) v += y; }
    __shared__ int wsum[4];
    if (lane == 63) wsum[wid] = v;
    __syncthreads();
    int add = 0;
    for (int w = 0; w < wid; ++w) add += wsum[w];
    int excl = v + add - ps;
    ofs[2 * tid] = excl; ofs[2 * tid + 1] = excl + a0;
    cur[2 * tid] = excl; cur[2 * tid + 1] = excl + a0;
    __syncthreads();

    // rowptr for this bin's nodes
    int nodeBase = b << BINB;
    #pragma unroll
    for (int j = 0; j < 2; ++j) {
        int i = tid + j * 256;
        int n = nodeBase + i;
        if (n < NN) rowptr[n] = s + ofs[i];
    }

    // place srcs
    for (int e = s + tid; e < t; e += 256) {
        unsigned p = binpair[e];
        int l = p & (BINSZ - 1);
        int pos = s + atomicAdd(&cur[l], 1);
        eidx[pos] = (int)(p >> BINB);
    }
}

// ---------------- fused Linear + LayerNorm + ReLU ----------------
// wave = 4 nodes, lane = output feature. W staged in LDS; 16 node-rows/block staged in LDS.
// NOTE: hout may alias in0 (in-place, node-wise) -> no __restrict__ on these.

__device__ __forceinline__ float wave_sum64(float v) {
    #pragma unroll
    for (int d = 32; d >= 1; d >>= 1) v += __shfl_xor(v, d);
    return v;
}

__global__ __launch_bounds__(256) void k_mlp(
    const float* in0, int s0,
    const float* in1, int s1,
    const float* __restrict__ W,   const float* __restrict__ bias,
    const float* __restrict__ gam, const float* __restrict__ bet,
    float* hout, int ostride)
{
    __shared__ float sW[INF * HID];      // 32 KB
    __shared__ float sV[16 * INF];       // 8 KB: 16 node-rows of 128
    __shared__ float sB[HID], sG[HID], sBe[HID];

    int tid = threadIdx.x, lane = tid & 63, wid = tid >> 6;

    {   // stage W (+params) once
        const float4* Wg = (const float4*)W;
        float4* sW4 = (float4*)sW;
        #pragma unroll
        for (int j = 0; j < 8; ++j) sW4[tid + j * 256] = Wg[tid + j * 256];
        if (tid < HID) { sB[tid] = bias[tid]; sG[tid] = gam[tid]; sBe[tid] = bet[tid]; }
    }

    const int NG = NN / 16;  // 6250 groups of 16 nodes
    for (int g = blockIdx.x; g < NG; g += gridDim.x) {
        int base = g * 16;
        __syncthreads();
        {   // stage 16 rows (512 float4): coalesced
            float4* sV4 = (float4*)sV;
            #pragma unroll
            for (int t = 0; t < 2; ++t) {
                int f4 = tid + t * 256;
                int nl = f4 >> 5, k4 = f4 & 31;
                int n = base + nl;
                const float* p = (k4 < 16) ? (in0 + (size_t)n * s0 + k4 * 4)
                                           : (in1 + (size_t)n * s1 + (k4 - 16) * 4);
                sV4[f4] = *(const float4*)p;
            }
        }
        __syncthreads();

        const float4* v0 = (const float4*)sV + (wid * 4 + 0) * 32;
        const float4* v1 = v0 + 32;
        const float4* v2 = v0 + 64;
        const float4* v3 = v0 + 96;
        float acc0 = 0.f, acc1 = 0.f, acc2 = 0.f, acc3 = 0.f;
        #pragma unroll
        for (int k4 = 0; k4 < 32; ++k4) {
            float4 a = v0[k4], b = v1[k4], c = v2[k4], d = v3[k4];
            const float* wrow = &sW[k4 * 4 * HID + lane];
            float w0 = wrow[0], w1 = wrow[64], w2 = wrow[128], w3 = wrow[192];
            acc0 = fmaf(a.x, w0, acc0); acc0 = fmaf(a.y, w1, acc0);
            acc0 = fmaf(a.z, w2, acc0); acc0 = fmaf(a.w, w3, acc0);
            acc1 = fmaf(b.x, w0, acc1); acc1 = fmaf(b.y, w1, acc1);
            acc1 = fmaf(b.z, w2, acc1); acc1 = fmaf(b.w, w3, acc1);
            acc2 = fmaf(c.x, w0, acc2); acc2 = fmaf(c.y, w1, acc2);
            acc2 = fmaf(c.z, w2, acc2); acc2 = fmaf(c.w, w3, acc2);
            acc3 = fmaf(d.x, w0, acc3); acc3 = fmaf(d.y, w1, acc3);
            acc3 = fmaf(d.z, w2, acc3); acc3 = fmaf(d.w, w3, acc3);
        }

        int n0 = base + wid * 4;
        float accs[4] = {acc0, acc1, acc2, acc3};
        #pragma unroll
        for (int p = 0; p < 4; ++p) {
            float acc = accs[p] + sB[lane];
            float s  = wave_sum64(acc);
            float ss = wave_sum64(acc * acc);
            float mu  = s * 0.015625f;
            float var = fmaxf(ss * 0.015625f - mu * mu, 0.f);
            float rs  = rsqrtf(var + LN_EPS);
            float o   = (acc - mu) * rs * sG[lane] + sBe[lane];
            hout[(size_t)(n0 + p) * ostride + lane] = fmaxf(o, 0.f);
        }
    }
}

// ---------------- per-dst segment max (gather over CSR) ----------------
// wave per node, lane = feature. h >= 0 (post-ReLU) so init 0 is the max identity.

__global__ __launch_bounds__(256) void k_gather(
    const float* __restrict__ h, int hstride,
    const int* __restrict__ rowptr, const int* __restrict__ eidx,
    float* __restrict__ agg, int astride)
{
    int lane = threadIdx.x & 63;
    int n = blockIdx.x * 4 + (threadIdx.x >> 6);
    if (n >= NN) return;
    int start = rowptr[n], end = rowptr[n + 1];
    float m;
    if (start == end) {
        m = h[(size_t)n * hstride + lane];   // no in-edges: keep own feature
    } else {
        m = 0.f;
        int e = start;
        for (; e + 4 <= end; e += 4) {
            int i0 = eidx[e], i1 = eidx[e + 1], i2 = eidx[e + 2], i3 = eidx[e + 3];
            float a = h[(size_t)i0 * hstride + lane], b = h[(size_t)i1 * hstride + lane];
            float c = h[(size_t)i2 * hstride + lane], d = h[(size_t)i3 * hstride + lane];
            m = fmaxf(m, fmaxf(fmaxf(a, b), fmaxf(c, d)));
        }
        for (; e < end; ++e) m = fmaxf(m, h[(size_t)eidx[e] * hstride + lane]);
    }
    agg[(size_t)n * astride + lane] = m;
}

// ---------------- launch ----------------

extern "C" void kernel_launch(void* const* d_in, const int* in_sizes, int n_in,
                              void* d_out, int out_size, void* d_ws, size_t ws_size,
                              hipStream_t stream) {
    const float* inputs = (const float*)d_in[0];
    const int*   src    = (const int*)d_in[1];
    const int*   dst    = (const int*)d_in[2];
    const float* Ws     = (const float*)d_in[3];
    const float* bs     = (const float*)d_in[4];
    const float* gs     = (const float*)d_in[5];
    const float* bes    = (const float*)d_in[6];
    float* out = (float*)d_out;

    char* w = (char*)d_ws;
    int* bincnt = (int*)w; w += 256 * 4;
    int* binptr = (int*)w; w += 256 * 4;
    int* bincur = (int*)w; w += 256 * 4;
    int* rowptr = (int*)w; w += (size_t)(NN + 1) * 4;
    int* eidx   = (int*)w; w += (size_t)NE * 4;
    uintptr_t a = (uintptr_t)w; a = (a + 255) & ~(uintptr_t)255; w = (char*)a;
    float* hA   = (float*)w; w += (size_t)NN * HID * 4;
    float* aggA = (float*)w; w += (size_t)NN * HID * 4;
    // binpair aliases aggA's space: dead before aggA's first write (stream-ordered)
    unsigned* binpair = (unsigned*)aggA;

    // CSR build (graph is layer-invariant within a call)
    k_zero   <<<1,    256, 0, stream>>>(bincnt);
    k_binhist<<<391,  256, 0, stream>>>(dst, bincnt);
    k_binscan<<<1,    256, 0, stream>>>(bincnt, binptr, bincur, rowptr);
    k_binfill<<<FILLB, 256, 0, stream>>>(src, dst, bincur, binpair);
    k_binsort<<<NBIN, 256, 0, stream>>>(binpair, binptr, rowptr, eidx);

    // layer 0: inputs -> hA, aggA
    k_mlp   <<<1250, 256, 0, stream>>>(inputs, INF, inputs + HID, INF, Ws, bs, gs, bes, hA, HID);
    k_gather<<<25000, 256, 0, stream>>>(hA, HID, rowptr, eidx, aggA, HID);
    // layer 1: in-place (node-wise map; block stages its 16 rows before storing)
    k_mlp   <<<1250, 256, 0, stream>>>(hA, HID, aggA, HID, Ws + 8192, bs + 64, gs + 64, bes + 64, hA, HID);
    k_gather<<<25000, 256, 0, stream>>>(hA, HID, rowptr, eidx, aggA, HID);
    // layer 2: h -> out interleaved [n][0:64], agg -> out [n][64:128]
    k_mlp   <<<1250, 256, 0, stream>>>(hA, HID, aggA, HID, Ws + 16384, bs + 128, gs + 128, bes + 128, out, 2 * HID);
    k_gather<<<25000, 256, 0, stream>>>(out, 2 * HID, rowptr, eidx, out + HID, 2 * HID);
}

// Round 5
// 372.513 us; speedup vs baseline: 3.4902x; 1.1391x over previous
//
#include <hip/hip_runtime.h>

#define NN 100000
#define NE 1600000
#define INF 128
#define HID 64
#define LN_EPS 1e-5f

#define BINB 9
#define BINSZ 512
#define NBIN 196   // ceil(100000/512)
#define FILLB 512  // blocks in k_binfill

#define XPAD 132   // row stride (floats) for sX: 16B-aligned, 8-way aliasing on read (acceptable)

// ---------------- CSR build via binned counting sort ----------------

__global__ __launch_bounds__(256) void k_zero(int* __restrict__ bincnt) {
    int i = threadIdx.x;
    if (i < NBIN) bincnt[i] = 0;
}

__global__ __launch_bounds__(256) void k_binhist(const int* __restrict__ dst, int* __restrict__ bincnt) {
    __shared__ int h[NBIN];
    for (int i = threadIdx.x; i < NBIN; i += 256) h[i] = 0;
    __syncthreads();
    int stride = gridDim.x * 256;
    for (int e = blockIdx.x * 256 + threadIdx.x; e < NE; e += stride)
        atomicAdd(&h[dst[e] >> BINB], 1);
    __syncthreads();
    for (int i = threadIdx.x; i < NBIN; i += 256)
        if (h[i]) atomicAdd(&bincnt[i], h[i]);
}

__global__ __launch_bounds__(256) void k_binscan(const int* __restrict__ bincnt, int* __restrict__ binptr,
                                                 int* __restrict__ bincur, int* __restrict__ rowptr) {
    int tid = threadIdx.x, lane = tid & 63, wid = tid >> 6;
    int x = (tid < NBIN) ? bincnt[tid] : 0;
    int v = x;
    #pragma unroll
    for (int d = 1; d < 64; d <<= 1) { int y = __shfl_up(v, d); if (lane >= d) v += y; }
    __shared__ int wsum[4];
    if (lane == 63) wsum[wid] = v;
    __syncthreads();
    int add = 0;
    for (int w = 0; w < wid; ++w) add += wsum[w];
    int excl = v + add - x;
    if (tid < NBIN) { binptr[tid] = excl; bincur[tid] = excl; }
    if (tid == 0) { binptr[NBIN] = NE; rowptr[NN] = NE; }
}

// block-privatized: LDS histogram -> one global atomicAdd per (block,bin) -> LDS-cursor placement
__global__ __launch_bounds__(256) void k_binfill(const int* __restrict__ src, const int* __restrict__ dst,
                                                 int* __restrict__ bincur, unsigned* __restrict__ binpair) {
    __shared__ int cnt[NBIN];
    __shared__ int base[NBIN];
    __shared__ int cur[NBIN];
    int tid = threadIdx.x;
    const int chunk = (NE + FILLB - 1) / FILLB;          // 3125
    int s = blockIdx.x * chunk;
    int t = min(s + chunk, NE);

    for (int i = tid; i < NBIN; i += 256) cnt[i] = 0;
    __syncthreads();
    for (int e = s + tid; e < t; e += 256) atomicAdd(&cnt[dst[e] >> BINB], 1);
    __syncthreads();
    for (int i = tid; i < NBIN; i += 256) {
        int c = cnt[i];
        base[i] = c ? atomicAdd(&bincur[i], c) : 0;
        cur[i] = 0;
    }
    __syncthreads();
    for (int e = s + tid; e < t; e += 256) {
        int d = dst[e];
        int b = d >> BINB;
        int pos = base[b] + atomicAdd(&cur[b], 1);
        binpair[pos] = ((unsigned)src[e] << BINB) | (unsigned)(d & (BINSZ - 1));
    }
}

__global__ __launch_bounds__(256) void k_binsort(const unsigned* __restrict__ binpair,
                                                 const int* __restrict__ binptr,
                                                 int* __restrict__ rowptr, int* __restrict__ eidx) {
    __shared__ int cnt[BINSZ];
    __shared__ int ofs[BINSZ];
    __shared__ int cur[BINSZ];
    int tid = threadIdx.x, lane = tid & 63, wid = tid >> 6;
    int b = blockIdx.x;
    int s = binptr[b], t = binptr[b + 1];

    cnt[tid] = 0; cnt[tid + 256] = 0;
    __syncthreads();
    for (int e = s + tid; e < t; e += 256) atomicAdd(&cnt[binpair[e] & (BINSZ - 1)], 1);
    __syncthreads();

    // exclusive scan of cnt[512] with 256 threads (2 elems/thread)
    int a0 = cnt[2 * tid], a1 = cnt[2 * tid + 1];
    int ps = a0 + a1;
    int v = ps;
    #pragma unroll
    for (int d = 1; d < 64; d <<= 1) { int y = __shfl_up(v, d); if (lane >= d) v += y; }
    __shared__ int wsum[4];
    if (lane == 63) wsum[wid] = v;
    __syncthreads();
    int add = 0;
    for (int w = 0; w < wid; ++w) add += wsum[w];
    int excl = v + add - ps;
    ofs[2 * tid] = excl; ofs[2 * tid + 1] = excl + a0;
    cur[2 * tid] = excl; cur[2 * tid + 1] = excl + a0;
    __syncthreads();

    // rowptr for this bin's nodes
    int nodeBase = b << BINB;
    #pragma unroll
    for (int j = 0; j < 2; ++j) {
        int i = tid + j * 256;
        int n = nodeBase + i;
        if (n < NN) rowptr[n] = s + ofs[i];
    }

    // place srcs
    for (int e = s + tid; e < t; e += 256) {
        unsigned p = binpair[e];
        int l = p & (BINSZ - 1);
        int pos = s + atomicAdd(&cur[l], 1);
        eidx[pos] = (int)(p >> BINB);
    }
}

// ---------------- fused Linear + LayerNorm + ReLU (lane = node) ----------------
// Block = 256 threads = 4 waves; block owns 64 nodes; wave w owns features [16w,16w+16).
// x staged [64][XPAD] in LDS; W[k][f] is wave-uniform -> scalar loads, zero per-lane traffic.
// hout may alias in0/in1 (in-place node-wise) -> stores happen after full LDS staging.

__global__ __launch_bounds__(256) void k_mlp(
    const float* in0, int s0,
    const float* in1, int s1,
    const float* __restrict__ W,   const float* __restrict__ bias,
    const float* __restrict__ gam, const float* __restrict__ bet,
    float* hout, int ostride)
{
    __shared__ float sX[64 * XPAD];   // 33.8 KB
    __shared__ float sS[64 * 5];      // LN partial sums (padded stride 5)
    __shared__ float sQ[64 * 5];      // LN partial sumsq

    const int tid = threadIdx.x, lane = tid & 63;
    const int wid = __builtin_amdgcn_readfirstlane(tid >> 6);
    const int f0 = wid * 16;
    const int node0 = blockIdx.x * 64;

    // stage 64 node-rows (2048 float4, coalesced); clamp tail reads
    #pragma unroll
    for (int j = 0; j < 8; ++j) {
        int f4 = tid + j * 256;
        int nl = f4 >> 5, k4 = f4 & 31;
        int n = node0 + nl;
        if (n >= NN) n = NN - 1;
        const float* p = (k4 < 16) ? (in0 + (size_t)n * s0 + k4 * 4)
                                   : (in1 + (size_t)n * s1 + (k4 - 16) * 4);
        *(float4*)&sX[nl * XPAD + k4 * 4] = *(const float4*)p;
    }

    // per-wave uniform params (scalar loads)
    float bia[16], gma[16], bta[16];
    #pragma unroll
    for (int f = 0; f < 16; ++f) { bia[f] = bias[f0 + f]; gma[f] = gam[f0 + f]; bta[f] = bet[f0 + f]; }

    __syncthreads();

    float acc[16];
    #pragma unroll
    for (int f = 0; f < 16; ++f) acc[f] = bia[f];

    const float* xrow = &sX[lane * XPAD];
    const float* Wf = W + f0;
    #pragma unroll 4
    for (int k4 = 0; k4 < 32; ++k4) {
        float4 xv = *(const float4*)&xrow[k4 * 4];
        const float* Wk = Wf + (size_t)(k4 * 4) * HID;
        #pragma unroll
        for (int i = 0; i < 4; ++i) {
            float xi = (i == 0) ? xv.x : (i == 1) ? xv.y : (i == 2) ? xv.z : xv.w;
            float4 w0 = *(const float4*)(Wk + i * HID + 0);
            float4 w1 = *(const float4*)(Wk + i * HID + 4);
            float4 w2 = *(const float4*)(Wk + i * HID + 8);
            float4 w3 = *(const float4*)(Wk + i * HID + 12);
            acc[0]  = fmaf(xi, w0.x, acc[0]);  acc[1]  = fmaf(xi, w0.y, acc[1]);
            acc[2]  = fmaf(xi, w0.z, acc[2]);  acc[3]  = fmaf(xi, w0.w, acc[3]);
            acc[4]  = fmaf(xi, w1.x, acc[4]);  acc[5]  = fmaf(xi, w1.y, acc[5]);
            acc[6]  = fmaf(xi, w1.z, acc[6]);  acc[7]  = fmaf(xi, w1.w, acc[7]);
            acc[8]  = fmaf(xi, w2.x, acc[8]);  acc[9]  = fmaf(xi, w2.y, acc[9]);
            acc[10] = fmaf(xi, w2.z, acc[10]); acc[11] = fmaf(xi, w2.w, acc[11]);
            acc[12] = fmaf(xi, w3.x, acc[12]); acc[13] = fmaf(xi, w3.y, acc[13]);
            acc[14] = fmaf(xi, w3.z, acc[14]); acc[15] = fmaf(xi, w3.w, acc[15]);
        }
    }

    // LN: per-wave partials -> LDS -> block totals (all waves recompute identically)
    float s = 0.f, q = 0.f;
    #pragma unroll
    for (int f = 0; f < 16; ++f) { s += acc[f]; q += acc[f] * acc[f]; }
    sS[lane * 5 + wid] = s;
    sQ[lane * 5 + wid] = q;
    __syncthreads();
    float ts = 0.f, tq = 0.f;
    #pragma unroll
    for (int w = 0; w < 4; ++w) { ts += sS[lane * 5 + w]; tq += sQ[lane * 5 + w]; }
    float mu  = ts * 0.015625f;
    float var = fmaxf(tq * 0.015625f - mu * mu, 0.f);
    float rs  = rsqrtf(var + LN_EPS);

    int n = node0 + lane;
    if (n < NN) {
        float o[16];
        #pragma unroll
        for (int f = 0; f < 16; ++f)
            o[f] = fmaxf((acc[f] - mu) * rs * gma[f] + bta[f], 0.f);
        float* op = hout + (size_t)n * ostride + f0;
        *(float4*)(op + 0)  = make_float4(o[0], o[1], o[2], o[3]);
        *(float4*)(op + 4)  = make_float4(o[4], o[5], o[6], o[7]);
        *(float4*)(op + 8)  = make_float4(o[8], o[9], o[10], o[11]);
        *(float4*)(op + 12) = make_float4(o[12], o[13], o[14], o[15]);
    }
}

// ---------------- per-dst segment max (gather over CSR) ----------------
// wave per node, lane = feature. h >= 0 (post-ReLU) so init 0 is the max identity.

__global__ __launch_bounds__(256) void k_gather(
    const float* __restrict__ h, int hstride,
    const int* __restrict__ rowptr, const int* __restrict__ eidx,
    float* __restrict__ agg, int astride)
{
    int lane = threadIdx.x & 63;
    int n = blockIdx.x * 4 + (threadIdx.x >> 6);
    if (n >= NN) return;
    int start = rowptr[n], end = rowptr[n + 1];
    float m;
    if (start == end) {
        m = h[(size_t)n * hstride + lane];   // no in-edges: keep own feature
    } else {
        m = 0.f;
        int e = start;
        for (; e + 4 <= end; e += 4) {
            int i0 = eidx[e], i1 = eidx[e + 1], i2 = eidx[e + 2], i3 = eidx[e + 3];
            float a = h[(size_t)i0 * hstride + lane], b = h[(size_t)i1 * hstride + lane];
            float c = h[(size_t)i2 * hstride + lane], d = h[(size_t)i3 * hstride + lane];
            m = fmaxf(m, fmaxf(fmaxf(a, b), fmaxf(c, d)));
        }
        for (; e < end; ++e) m = fmaxf(m, h[(size_t)eidx[e] * hstride + lane]);
    }
    agg[(size_t)n * astride + lane] = m;
}

// ---------------- launch ----------------

extern "C" void kernel_launch(void* const* d_in, const int* in_sizes, int n_in,
                              void* d_out, int out_size, void* d_ws, size_t ws_size,
                              hipStream_t stream) {
    const float* inputs = (const float*)d_in[0];
    const int*   src    = (const int*)d_in[1];
    const int*   dst    = (const int*)d_in[2];
    const float* Ws     = (const float*)d_in[3];
    const float* bs     = (const float*)d_in[4];
    const float* gs     = (const float*)d_in[5];
    const float* bes    = (const float*)d_in[6];
    float* out = (float*)d_out;

    char* w = (char*)d_ws;
    int* bincnt = (int*)w; w += 256 * 4;
    int* binptr = (int*)w; w += 256 * 4;
    int* bincur = (int*)w; w += 256 * 4;
    int* rowptr = (int*)w; w += (size_t)(NN + 1) * 4;
    int* eidx   = (int*)w; w += (size_t)NE * 4;
    uintptr_t a = (uintptr_t)w; a = (a + 255) & ~(uintptr_t)255; w = (char*)a;
    float* hA   = (float*)w; w += (size_t)NN * HID * 4;
    float* aggA = (float*)w; w += (size_t)NN * HID * 4;
    // binpair aliases aggA's space: dead before aggA's first write (stream-ordered)
    unsigned* binpair = (unsigned*)aggA;

    const int MLPB = (NN + 63) / 64;   // 1563

    // CSR build (graph is layer-invariant within a call)
    k_zero   <<<1,    256, 0, stream>>>(bincnt);
    k_binhist<<<391,  256, 0, stream>>>(dst, bincnt);
    k_binscan<<<1,    256, 0, stream>>>(bincnt, binptr, bincur, rowptr);
    k_binfill<<<FILLB, 256, 0, stream>>>(src, dst, bincur, binpair);
    k_binsort<<<NBIN, 256, 0, stream>>>(binpair, binptr, rowptr, eidx);

    // layer 0: inputs -> hA, aggA
    k_mlp   <<<MLPB, 256, 0, stream>>>(inputs, INF, inputs + HID, INF, Ws, bs, gs, bes, hA, HID);
    k_gather<<<25000, 256, 0, stream>>>(hA, HID, rowptr, eidx, aggA, HID);
    // layer 1: in-place (node-wise map; block stages its 64 rows before storing)
    k_mlp   <<<MLPB, 256, 0, stream>>>(hA, HID, aggA, HID, Ws + 8192, bs + 64, gs + 64, bes + 64, hA, HID);
    k_gather<<<25000, 256, 0, stream>>>(hA, HID, rowptr, eidx, aggA, HID);
    // layer 2: h -> out interleaved [n][0:64], agg -> out [n][64:128]
    k_mlp   <<<MLPB, 256, 0, stream>>>(hA, HID, aggA, HID, Ws + 16384, bs + 128, gs + 128, bes + 128, out, 2 * HID);
    k_gather<<<25000, 256, 0, stream>>>(out, 2 * HID, rowptr, eidx, out + HID, 2 * HID);
}